// Round 4
// baseline (35175.760 us; speedup 1.0000x reference)
//
#include <hip/hip_runtime.h>

typedef __bf16 bf16;
typedef __bf16 bf16x8 __attribute__((ext_vector_type(8)));
typedef __bf16 bf16x4 __attribute__((ext_vector_type(4)));
typedef float f32x4 __attribute__((ext_vector_type(4)));

#define SCOPE_AGENT __HIP_MEMORY_SCOPE_AGENT

// B=32, T=256, H=1024, HY=256, E=64, L=2
// d_out = h_seq (32,256,1024) ++ h_last (32,1024) ++ c_last (32,1024), fp32

__device__ __forceinline__ float sigf(float x) { return 1.0f / (1.0f + __expf(-x)); }
__device__ __forceinline__ float tanhf_fast(float x) {
  float e = __expf(-2.0f * fabsf(x));
  float r = (1.0f - e) / (1.0f + e);
  return copysignf(r, x);
}
__device__ __forceinline__ f32x4 mfma16(bf16x8 a, bf16x8 b, f32x4 c) {
  return __builtin_amdgcn_mfma_f32_16x16x32_bf16(a, b, c, 0, 0, 0);
}

// ---------------- dtype detector: read probe as bf16; fp32 bits -> wild values ------
__global__ void detect_kernel(const void* probe, int* flag) {
  __shared__ int cnt;
  if (threadIdx.x == 0) cnt = 0;
  __syncthreads();
  const bf16* p = (const bf16*)probe;
  int local = 0;
  for (int j = threadIdx.x; j < 8192; j += 256) {
    float x = (float)p[j];
    bool wild = (x != x) || (fabsf(x) > 1e3f) || (x != 0.0f && fabsf(x) < 1e-30f);
    local += wild ? 1 : 0;
  }
  atomicAdd(&cnt, local);
  __syncthreads();
  if (threadIdx.x == 0) *flag = (cnt > 64) ? 1 : 0;   // 1 == inputs are fp32
}

// ---------------- convert all 15 tensors to canonical bf16 copies ----------------
struct CvtSrc { const void* s[15]; };
struct CvtDst { bf16* d[15]; };

__global__ __launch_bounds__(256) void convert_kernel(CvtSrc S, CvtDst D, const int* flag) {
  const int pre[16] = {0, 8388608, 16777216, 25165824, 29360128, 29884416, 29886464,
                       30017536, 30018048, 30149120, 30149632, 30280704, 30804992,
                       31329280, 31853568, 31861760};
  const int fp32 = *flag;
  const int nvec = 31861760 / 4;
  for (int v = blockIdx.x * 256 + threadIdx.x; v < nvec; v += gridDim.x * 256) {
    int e = v * 4;
    int seg = 0;
#pragma unroll
    for (int k = 1; k < 15; ++k) seg += (e >= pre[k]) ? 1 : 0;
    int off = e - pre[seg];
    bf16* d = D.d[seg] + off;
    if (fp32) {
      const float* s = (const float*)S.s[seg] + off;
      float4 x = *(const float4*)s;
      d[0] = (bf16)x.x; d[1] = (bf16)x.y; d[2] = (bf16)x.z; d[3] = (bf16)x.w;
    } else {
      const bf16* s = (const bf16*)S.s[seg] + off;
      d[0] = s[0]; d[1] = s[1]; d[2] = s[2]; d[3] = s[3];
    }
  }
}

// ---------------- init: zero states + flags ----------------
__global__ void init_kernel(float* cst, float* hcst, bf16* h_bf, bf16* hh_bf, int* flags) {
  int i = blockIdx.x * 256 + threadIdx.x;   // 128 blocks -> 32768 threads
  cst[i] = 0.0f;                            // 32*1024
  h_bf[i] = (bf16)0.0f;                     // 32*1024
  if (i < 8192) { hcst[i] = 0.0f; hh_bf[i] = (bf16)0.0f; }  // 32*256
  if (i < 4096) flags[i] = 0;
}

// ---------------- precompute GEMM: C[8192 x 5120] = A[8192x1024] * W[5120x1024]^T ----
// n in [0,4096): W row = w_ih_l[n]       -> Xp  (bf16)
// n in [4096,5120): W row = hwih_l[n-4096][0:1024] (x-part, row stride 2048) -> Hxp (f32)
__global__ __launch_bounds__(256) void gemm_pre(
    const bf16* __restrict__ A, const bf16* __restrict__ w_ih_l,
    const bf16* __restrict__ hwih_l, bf16* __restrict__ Xp, float* __restrict__ Hxp) {
  constexpr int LDT = 72;
  __shared__ alignas(16) bf16 As[64 * LDT];
  __shared__ alignas(16) bf16 Bs[64 * LDT];
  const int bm = blockIdx.x & 127;     // 128 M-tiles of 64
  const int bn = blockIdx.x >> 7;      // 80 N-tiles of 64
  const int m0 = bm * 64, n0 = bn * 64;
  const int tid = threadIdx.x;
  const int lane = tid & 63, wid = tid >> 6;
  const int l15 = lane & 15, q = lane >> 4;
  const int srow = tid >> 2, sk = (tid & 3) * 16;
  const bf16* arow = A + (size_t)(m0 + srow) * 1024;
  const int n = n0 + srow;
  const bf16* brow = (n < 4096) ? (w_ih_l + (size_t)n * 1024)
                                : (hwih_l + (size_t)(n - 4096) * 2048);
  f32x4 acc[4] = {};
  for (int kb = 0; kb < 1024; kb += 64) {
    *(bf16x8*)(&As[srow * LDT + sk])     = *(const bf16x8*)(arow + kb + sk);
    *(bf16x8*)(&As[srow * LDT + sk + 8]) = *(const bf16x8*)(arow + kb + sk + 8);
    *(bf16x8*)(&Bs[srow * LDT + sk])     = *(const bf16x8*)(brow + kb + sk);
    *(bf16x8*)(&Bs[srow * LDT + sk + 8]) = *(const bf16x8*)(brow + kb + sk + 8);
    __syncthreads();
#pragma unroll
    for (int kk = 0; kk < 64; kk += 32) {
      bf16x8 av = *(const bf16x8*)(&As[(wid * 16 + l15) * LDT + kk + q * 8]);
#pragma unroll
      for (int j = 0; j < 4; ++j) {
        bf16x8 bv = *(const bf16x8*)(&Bs[(j * 16 + l15) * LDT + kk + q * 8]);
        acc[j] = mfma16(av, bv, acc[j]);
      }
    }
    __syncthreads();
  }
#pragma unroll
  for (int j = 0; j < 4; ++j) {
    const int gn = n0 + j * 16 + l15;
#pragma unroll
    for (int r = 0; r < 4; ++r) {
      const int gm = m0 + wid * 16 + q * 4 + r;
      float v = acc[j][r];
      if (gn < 4096) Xp[(size_t)gm * 4096 + gn] = (bf16)v;
      else           Hxp[(size_t)gm * 1024 + (gn - 4096)] = v;
    }
  }
}

// ------- two-level grid barrier; 128 blocks co-resident on 256 CUs (regular launch,
//         4 waves/CU, 11KB LDS -> residency guaranteed by capacity) -------
__device__ __forceinline__ void grid_barrier(int* flags, int epoch) {
  __syncthreads();
  if (threadIdx.x == 0) {
    __builtin_amdgcn_fence(__ATOMIC_RELEASE, "agent");
    int* gen  = flags;
    int* topc = flags + 32;
    int* gcnt = flags + 64 + (blockIdx.x >> 3) * 32;   // 16 groups of 8 blocks
    int p = __hip_atomic_fetch_add(gcnt, 1, __ATOMIC_RELAXED, SCOPE_AGENT);
    if (p == 7) {
      __hip_atomic_store(gcnt, 0, __ATOMIC_RELAXED, SCOPE_AGENT);
      int qq = __hip_atomic_fetch_add(topc, 1, __ATOMIC_RELAXED, SCOPE_AGENT);
      if (qq == 15) {
        __hip_atomic_store(topc, 0, __ATOMIC_RELAXED, SCOPE_AGENT);
        __hip_atomic_store(gen, epoch, __ATOMIC_RELEASE, SCOPE_AGENT);
      }
    }
    while (__hip_atomic_load(gen, __ATOMIC_RELAXED, SCOPE_AGENT) < epoch) {}
    __builtin_amdgcn_fence(__ATOMIC_ACQUIRE, "agent");
  }
  __syncthreads();
}

struct SeqArgs {
  int layer;
  const bf16 *w_hh, *hwih, *hwhh, *hyb;
  const bf16 *w_zh, *b_zh, *w_zx, *b_zx, *w_zb;
  const bf16 *w_dh, *w_dx, *w_db, *b0;
  const bf16 *Xp; const float *Hxp;
  float *Rh, *hg, *zbuf, *cst, *hcst;
  bf16 *h_bf, *hh_bf, *Y0;
  float *outp;
  int *flags;
};

// ---------------- persistent sequential kernel: 256 steps of one layer -------------
__global__ __launch_bounds__(256) void seq_kernel(SeqArgs a) {
  __shared__ alignas(16) float zs[1536];   // z for 2 batch elems: [i][tau*256 + g*64+e]
  __shared__ float pres[1024];             // [i][g][128]
  __shared__ float hh2s[256];
  const int tid = threadIdx.x;
  const int lane = tid & 63, wid = tid >> 6;
  const int l15 = lane & 15, q = lane >> 4;
  const int gw = blockIdx.x * 4 + wid;     // global wave id, [0,512)
  const int sub = blockIdx.x & 7;          // h-slice id   (BC role)
  const int bp  = blockIdx.x >> 3;         // batch pair   (BC role, [0,16))
  const int layer = a.layer;
  const bf16* whh_l  = a.w_hh + (size_t)layer * 4096 * 1024;
  const bf16* hwih_l = a.hwih + (size_t)layer * 1024 * 2048;
  const bf16* hwhh_l = a.hwhh + (size_t)layer * 1024 * 256;
  int* zflg = a.flags + 64 + 16 * 32;      // flags+576, one slot per batch elem (stride 32)
  int epoch = 0;

  for (int t = 0; t < 256; ++t) {
    // ---- phase A: Rh = h@w_hh^T (32x4096); hg = h@hWih_h^T + hh@hWhh^T (32x1024) ----
    if (gw < 256) {            // Rh n-tile
      const int nt = gw;
      const bf16* brow = whh_l + (size_t)(nt * 16 + l15) * 1024;
      const bf16* ar0 = a.h_bf + l15 * 1024;
      const bf16* ar1 = a.h_bf + (16 + l15) * 1024;
      f32x4 c0 = {}, c1 = {};
#pragma unroll 4
      for (int k = 0; k < 1024; k += 32) {
        const int ko = k + q * 8;
        bf16x8 bv = *(const bf16x8*)(brow + ko);
        bf16x8 a0 = *(const bf16x8*)(ar0 + ko);
        bf16x8 a1 = *(const bf16x8*)(ar1 + ko);
        c0 = mfma16(a0, bv, c0); c1 = mfma16(a1, bv, c1);
      }
      const int n = nt * 16 + l15;
#pragma unroll
      for (int r = 0; r < 4; ++r) {
        a.Rh[(q * 4 + r) * 4096 + n] = c0[r];
        a.Rh[(16 + q * 4 + r) * 4096 + n] = c1[r];
      }
    } else if (gw < 320) {     // hyper-gate n-tile
      const int nt = gw - 256;
      const bf16* brow = hwih_l + (size_t)(nt * 16 + l15) * 2048 + 1024;  // h-part cols
      const bf16* ar0 = a.h_bf + l15 * 1024;
      const bf16* ar1 = a.h_bf + (16 + l15) * 1024;
      f32x4 c0 = {}, c1 = {};
#pragma unroll 4
      for (int k = 0; k < 1024; k += 32) {
        const int ko = k + q * 8;
        bf16x8 bv = *(const bf16x8*)(brow + ko);
        bf16x8 a0 = *(const bf16x8*)(ar0 + ko);
        bf16x8 a1 = *(const bf16x8*)(ar1 + ko);
        c0 = mfma16(a0, bv, c0); c1 = mfma16(a1, bv, c1);
      }
      const bf16* brow2 = hwhh_l + (size_t)(nt * 16 + l15) * 256;
      const bf16* ah0 = a.hh_bf + l15 * 256;
      const bf16* ah1 = a.hh_bf + (16 + l15) * 256;
#pragma unroll
      for (int k = 0; k < 256; k += 32) {
        const int ko = k + q * 8;
        bf16x8 bv = *(const bf16x8*)(brow2 + ko);
        bf16x8 a0 = *(const bf16x8*)(ah0 + ko);
        bf16x8 a1 = *(const bf16x8*)(ah1 + ko);
        c0 = mfma16(a0, bv, c0); c1 = mfma16(a1, bv, c1);
      }
      const int n = nt * 16 + l15;
#pragma unroll
      for (int r = 0; r < 4; ++r) {
        a.hg[(q * 4 + r) * 1024 + n] = c0[r];
        a.hg[(16 + q * 4 + r) * 1024 + n] = c1[r];
      }
    }
    grid_barrier(a.flags, ++epoch);

    // ---- phase BC ----
    {
      if (sub < 2) {   // z producer for b = bp*2 + sub
        const int b = bp * 2 + sub;
        const int j = tid;
        const size_t hxo = ((size_t)b * 256 + t) * 1024;
        const bf16* hybl = a.hyb + (size_t)layer * 1024;
        float hi = a.hg[b * 1024 + j]       + (float)hybl[j]       + a.Hxp[hxo + j];
        float hf = a.hg[b * 1024 + 256 + j] + (float)hybl[256 + j] + a.Hxp[hxo + 256 + j];
        float hgc= a.hg[b * 1024 + 512 + j] + (float)hybl[512 + j] + a.Hxp[hxo + 512 + j];
        float ho = a.hg[b * 1024 + 768 + j] + (float)hybl[768 + j] + a.Hxp[hxo + 768 + j];
        float hcn = sigf(hf) * a.hcst[b * 256 + j] + sigf(hi) * tanhf_fast(hgc);
        float hhn = sigf(ho) * tanhf_fast(hcn);
        a.hcst[b * 256 + j] = hcn;
        a.hh_bf[b * 256 + j] = (bf16)hhn;
        hh2s[j] = hhn;
        __syncthreads();
        // z row = tid (= g*64+e), dot length 256 against hh2
        const bf16* wzt[3] = { a.w_zh + ((size_t)layer * 256 + tid) * 256,
                               a.w_zx + ((size_t)layer * 256 + tid) * 256,
                               a.w_zb + ((size_t)layer * 256 + tid) * 256 };
        float zb0[3] = { (float)a.b_zh[layer * 256 + tid], (float)a.b_zx[layer * 256 + tid], 0.0f };
#pragma unroll
        for (int tau = 0; tau < 3; ++tau) {
          float s = zb0[tau];
          for (int k0 = 0; k0 < 256; k0 += 8) {
            bf16x8 w8 = *(const bf16x8*)(wzt[tau] + k0);
#pragma unroll
            for (int jj = 0; jj < 8; ++jj) s += hh2s[k0 + jj] * (float)w8[jj];
          }
          a.zbuf[(size_t)b * 768 + tau * 256 + tid] = s;
        }
        __syncthreads();
        if (tid == 0) {
          __builtin_amdgcn_fence(__ATOMIC_RELEASE, "agent");
          __hip_atomic_store(&zflg[b * 32], t + 1, __ATOMIC_RELAXED, SCOPE_AGENT);
        }
      }
      // wait for both z halves of this batch pair
      if (tid == 0) {
        while (__hip_atomic_load(&zflg[(bp * 2 + 0) * 32], __ATOMIC_RELAXED, SCOPE_AGENT) < t + 1) {}
        while (__hip_atomic_load(&zflg[(bp * 2 + 1) * 32], __ATOMIC_RELAXED, SCOPE_AGENT) < t + 1) {}
        __builtin_amdgcn_fence(__ATOMIC_ACQUIRE, "agent");
      }
      __syncthreads();
#pragma unroll
      for (int r = 0; r < 6; ++r)
        zs[r * 256 + tid] = a.zbuf[(size_t)(bp * 2) * 768 + r * 256 + tid];
      __syncthreads();
      // d-projections + pre: wave = gate g, lanes = h; 2 h-halves x 2 batch elems
      const int g = wid, ha = lane;
      const size_t wb0 = (((size_t)layer * 4 + g) * 1024 + sub * 128 + ha) * 64;
      const size_t wb1 = wb0 + 64 * 64;
      const bf16 *wdh0 = a.w_dh + wb0, *wdh1 = a.w_dh + wb1;
      const bf16 *wdx0 = a.w_dx + wb0, *wdx1 = a.w_dx + wb1;
      const bf16 *wdb0 = a.w_db + wb0, *wdb1 = a.w_db + wb1;
      float dacc[12] = {};  // [tau*4 + i*2 + hh]
      for (int e0 = 0; e0 < 64; e0 += 4) {
        f32x4 zv[6];
#pragma unroll
        for (int tau = 0; tau < 3; ++tau)
#pragma unroll
          for (int i = 0; i < 2; ++i)
            zv[tau * 2 + i] = *(const f32x4*)&zs[i * 768 + tau * 256 + g * 64 + e0];
        bf16x4 wv[6];
        wv[0] = *(const bf16x4*)(wdh0 + e0); wv[1] = *(const bf16x4*)(wdh1 + e0);
        wv[2] = *(const bf16x4*)(wdx0 + e0); wv[3] = *(const bf16x4*)(wdx1 + e0);
        wv[4] = *(const bf16x4*)(wdb0 + e0); wv[5] = *(const bf16x4*)(wdb1 + e0);
#pragma unroll
        for (int jj = 0; jj < 4; ++jj)
#pragma unroll
          for (int tau = 0; tau < 3; ++tau)
#pragma unroll
            for (int hh = 0; hh < 2; ++hh) {
              float w = (float)wv[tau * 2 + hh][jj];
#pragma unroll
              for (int i = 0; i < 2; ++i)
                dacc[tau * 4 + i * 2 + hh] += zv[tau * 2 + i][jj] * w;
            }
      }
#pragma unroll
      for (int i = 0; i < 2; ++i)
#pragma unroll
        for (int hh = 0; hh < 2; ++hh) {
          const int b = bp * 2 + i;
          const int h = sub * 128 + hh * 64 + ha;
          const int nn = g * 1024 + h;
          float rh = a.Rh[b * 4096 + nn];
          float xp = (float)a.Xp[((size_t)b * 256 + t) * 4096 + nn];
          float b0v = (float)a.b0[(size_t)layer * 4096 + nn];
          pres[i * 512 + g * 128 + hh * 64 + ha] =
              dacc[0 + i * 2 + hh] * rh + dacc[4 + i * 2 + hh] * xp + dacc[8 + i * 2 + hh] + b0v;
        }
      __syncthreads();
      {
        const int i = tid >> 7, hloc = tid & 127;
        const int b = bp * 2 + i, h = sub * 128 + hloc;
        float iv = pres[i * 512 + hloc];
        float fv = pres[i * 512 + 128 + hloc];
        float gv = pres[i * 512 + 256 + hloc];
        float ov = pres[i * 512 + 384 + hloc];
        float cn = sigf(fv) * a.cst[b * 1024 + h] + sigf(iv) * tanhf_fast(gv);
        float hn = sigf(ov) * tanhf_fast(cn);
        a.cst[b * 1024 + h] = cn;
        a.h_bf[b * 1024 + h] = (bf16)hn;
        const size_t oo = ((size_t)b * 256 + t) * 1024 + h;
        if (layer == 0) a.Y0[oo] = (bf16)hn;
        else {
          a.outp[oo] = hn;
          if (t == 255) {
            a.outp[8388608 + b * 1024 + h] = hn;
            a.outp[8388608 + 32768 + b * 1024 + h] = cn;
          }
        }
      }
    }
    grid_barrier(a.flags, ++epoch);
  }
}

extern "C" void kernel_launch(void* const* d_in, const int* in_sizes, int n_in,
                              void* d_out, int out_size, void* d_ws, size_t ws_size,
                              hipStream_t stream) {
  float* outp = (float*)d_out;
  char* ws = (char*)d_ws;
  bf16*  Xp    = (bf16*) (ws);                      // 67,108,864 B
  float* Hxp   = (float*)(ws + 67108864ull);        // 33,554,432 B
  bf16*  Y0    = (bf16*) (ws + 100663296ull);       // 16,777,216 B
  float* Rh    = (float*)(ws + 117440512ull);       //    524,288 B
  float* hg    = (float*)(ws + 117964800ull);       //    131,072 B
  float* zbuf  = (float*)(ws + 118095872ull);       //     98,304 B
  float* cst   = (float*)(ws + 118194176ull);       //    131,072 B
  float* hcst  = (float*)(ws + 118325248ull);       //     32,768 B
  bf16*  h_bf  = (bf16*) (ws + 118358016ull);       //     65,536 B
  bf16*  hh_bf = (bf16*) (ws + 118423552ull);       //     16,384 B
  int*   flags = (int*)  (ws + 118439936ull);       //     16,384 B
  // canonical bf16 copies of the 15 inputs
  bf16* c_input = (bf16*)(ws + 118456320ull);       // 16,777,216 B
  bf16* c_w_ih  = (bf16*)(ws + 135233536ull);       // 16,777,216 B
  bf16* c_w_hh  = (bf16*)(ws + 152010752ull);       // 16,777,216 B
  bf16* c_hwih  = (bf16*)(ws + 168787968ull);       //  8,388,608 B
  bf16* c_hwhh  = (bf16*)(ws + 177176576ull);       //  1,048,576 B
  bf16* c_hyb   = (bf16*)(ws + 178225152ull);       //      4,096 B
  bf16* c_wzh   = (bf16*)(ws + 178229248ull);       //    262,144 B
  bf16* c_bzh   = (bf16*)(ws + 178491392ull);       //      1,024 B
  bf16* c_wzx   = (bf16*)(ws + 178492416ull);       //    262,144 B
  bf16* c_bzx   = (bf16*)(ws + 178754560ull);       //      1,024 B
  bf16* c_wzb   = (bf16*)(ws + 178755584ull);       //    262,144 B
  bf16* c_wdh   = (bf16*)(ws + 179017728ull);       //  1,048,576 B
  bf16* c_wdx   = (bf16*)(ws + 180066304ull);       //  1,048,576 B
  bf16* c_wdb   = (bf16*)(ws + 181114880ull);       //  1,048,576 B
  bf16* c_b0    = (bf16*)(ws + 182163456ull);       //     16,384 B
  int*  dflag   = (int*) (ws + 182179840ull);       //          4 B

  hipLaunchKernelGGL(detect_kernel, dim3(1), dim3(256), 0, stream, d_in[2], dflag);
  CvtSrc S; CvtDst D;
  for (int i = 0; i < 15; ++i) S.s[i] = d_in[i];
  D.d[0] = c_input; D.d[1] = c_w_ih; D.d[2] = c_w_hh; D.d[3] = c_hwih; D.d[4] = c_hwhh;
  D.d[5] = c_hyb;   D.d[6] = c_wzh;  D.d[7] = c_bzh;  D.d[8] = c_wzx;  D.d[9] = c_bzx;
  D.d[10] = c_wzb;  D.d[11] = c_wdh; D.d[12] = c_wdx; D.d[13] = c_wdb; D.d[14] = c_b0;
  hipLaunchKernelGGL(convert_kernel, dim3(2048), dim3(256), 0, stream, S, D, dflag);

  for (int layer = 0; layer < 2; ++layer) {
    hipLaunchKernelGGL(init_kernel, dim3(128), dim3(256), 0, stream,
                       cst, hcst, h_bf, hh_bf, flags);
    const bf16* A = (layer == 0) ? c_input : Y0;
    hipLaunchKernelGGL(gemm_pre, dim3(10240), dim3(256), 0, stream,
                       A, c_w_ih + (size_t)layer * 4096 * 1024,
                       c_hwih + (size_t)layer * 1024 * 2048, Xp, Hxp);
    SeqArgs sa;
    sa.layer = layer;
    sa.w_hh = c_w_hh; sa.hwih = c_hwih; sa.hwhh = c_hwhh; sa.hyb = c_hyb;
    sa.w_zh = c_wzh; sa.b_zh = c_bzh; sa.w_zx = c_wzx; sa.b_zx = c_bzx; sa.w_zb = c_wzb;
    sa.w_dh = c_wdh; sa.w_dx = c_wdx; sa.w_db = c_wdb; sa.b0 = c_b0;
    sa.Xp = Xp; sa.Hxp = Hxp;
    sa.Rh = Rh; sa.hg = hg; sa.zbuf = zbuf; sa.cst = cst; sa.hcst = hcst;
    sa.h_bf = h_bf; sa.hh_bf = hh_bf; sa.Y0 = Y0; sa.outp = outp;
    sa.flags = flags;
    hipLaunchKernelGGL(seq_kernel, dim3(128), dim3(256), 0, stream, sa);
  }
}

// Round 5
// 32417.697 us; speedup vs baseline: 1.0851x; 1.0851x over previous
//
#include <hip/hip_runtime.h>

typedef __bf16 bf16;
typedef __bf16 bf16x8 __attribute__((ext_vector_type(8)));
typedef __bf16 bf16x4 __attribute__((ext_vector_type(4)));
typedef float f32x4 __attribute__((ext_vector_type(4)));
typedef unsigned long long u64;

#define SCOPE_AGENT __HIP_MEMORY_SCOPE_AGENT

// B=32, T=256, H=1024, HY=256, E=64, L=2
// d_out = h_seq (32,256,1024) ++ h_last (32,1024) ++ c_last (32,1024), fp32

__device__ __forceinline__ float sigf(float x) { return 1.0f / (1.0f + __expf(-x)); }
__device__ __forceinline__ float tanhf_fast(float x) {
  float e = __expf(-2.0f * fabsf(x));
  float r = (1.0f - e) / (1.0f + e);
  return copysignf(r, x);
}
__device__ __forceinline__ f32x4 mfma16(bf16x8 a, bf16x8 b, f32x4 c) {
  return __builtin_amdgcn_mfma_f32_16x16x32_bf16(a, b, c, 0, 0, 0);
}
// Agent-scope (MALL-coherent) primitives: NO fences -> no buffer_wbl2/buffer_inv.
__device__ __forceinline__ u64 uld(const u64* p) { return __hip_atomic_load(p, __ATOMIC_RELAXED, SCOPE_AGENT); }
__device__ __forceinline__ void ust(u64* p, u64 v) { __hip_atomic_store(p, v, __ATOMIC_RELAXED, SCOPE_AGENT); }
__device__ __forceinline__ int ildi(const int* p) { return __hip_atomic_load(p, __ATOMIC_RELAXED, SCOPE_AGENT); }
__device__ __forceinline__ void isti(int* p, int v) { __hip_atomic_store(p, v, __ATOMIC_RELAXED, SCOPE_AGENT); }
__device__ __forceinline__ void fstf(float* p, float v) { __hip_atomic_store(p, v, __ATOMIC_RELAXED, SCOPE_AGENT); }

// ---------------- dtype detector ----------------
__global__ void detect_kernel(const void* probe, int* flag) {
  __shared__ int cnt;
  if (threadIdx.x == 0) cnt = 0;
  __syncthreads();
  const bf16* p = (const bf16*)probe;
  int local = 0;
  for (int j = threadIdx.x; j < 8192; j += 256) {
    float x = (float)p[j];
    bool wild = (x != x) || (fabsf(x) > 1e3f) || (x != 0.0f && fabsf(x) < 1e-30f);
    local += wild ? 1 : 0;
  }
  atomicAdd(&cnt, local);
  __syncthreads();
  if (threadIdx.x == 0) *flag = (cnt > 64) ? 1 : 0;
}

// ---------------- convert 15 tensors to canonical bf16 ----------------
struct CvtSrc { const void* s[15]; };
struct CvtDst { bf16* d[15]; };

__global__ __launch_bounds__(256) void convert_kernel(CvtSrc S, CvtDst D, const int* flag) {
  const int pre[16] = {0, 8388608, 16777216, 25165824, 29360128, 29884416, 29886464,
                       30017536, 30018048, 30149120, 30149632, 30280704, 30804992,
                       31329280, 31853568, 31861760};
  const int fp32 = *flag;
  const int nvec = 31861760 / 4;
  for (int v = blockIdx.x * 256 + threadIdx.x; v < nvec; v += gridDim.x * 256) {
    int e = v * 4;
    int seg = 0;
#pragma unroll
    for (int k = 1; k < 15; ++k) seg += (e >= pre[k]) ? 1 : 0;
    int off = e - pre[seg];
    bf16* d = D.d[seg] + off;
    if (fp32) {
      const float* s = (const float*)S.s[seg] + off;
      float4 x = *(const float4*)s;
      d[0] = (bf16)x.x; d[1] = (bf16)x.y; d[2] = (bf16)x.z; d[3] = (bf16)x.w;
    } else {
      const bf16* s = (const bf16*)S.s[seg] + off;
      d[0] = s[0]; d[1] = s[1]; d[2] = s[2]; d[3] = s[3];
    }
  }
}

// ---------------- init: zero h/hh publish buffers + flags ----------------
__global__ void init_kernel(u64* hpub, u64* hhpub, int* flags) {
  int i = blockIdx.x * 256 + threadIdx.x;   // 32 blocks -> 8192 threads
  hpub[i] = 0ull;                           // 32*256 u64
  if (i < 2048) hhpub[i] = 0ull;            // 32*64 u64
  if (i < 4096) flags[i] = 0;
}

// ---------------- precompute GEMM (unchanged from round 4, verified) ----------------
__global__ __launch_bounds__(256) void gemm_pre(
    const bf16* __restrict__ A, const bf16* __restrict__ w_ih_l,
    const bf16* __restrict__ hwih_l, bf16* __restrict__ Xp, float* __restrict__ Hxp) {
  constexpr int LDT = 72;
  __shared__ alignas(16) bf16 As[64 * LDT];
  __shared__ alignas(16) bf16 Bs[64 * LDT];
  const int bm = blockIdx.x & 127;
  const int bn = blockIdx.x >> 7;
  const int m0 = bm * 64, n0 = bn * 64;
  const int tid = threadIdx.x;
  const int lane = tid & 63, wid = tid >> 6;
  const int l15 = lane & 15, q = lane >> 4;
  const int srow = tid >> 2, sk = (tid & 3) * 16;
  const bf16* arow = A + (size_t)(m0 + srow) * 1024;
  const int n = n0 + srow;
  const bf16* brow = (n < 4096) ? (w_ih_l + (size_t)n * 1024)
                                : (hwih_l + (size_t)(n - 4096) * 2048);
  f32x4 acc[4] = {};
  for (int kb = 0; kb < 1024; kb += 64) {
    *(bf16x8*)(&As[srow * LDT + sk])     = *(const bf16x8*)(arow + kb + sk);
    *(bf16x8*)(&As[srow * LDT + sk + 8]) = *(const bf16x8*)(arow + kb + sk + 8);
    *(bf16x8*)(&Bs[srow * LDT + sk])     = *(const bf16x8*)(brow + kb + sk);
    *(bf16x8*)(&Bs[srow * LDT + sk + 8]) = *(const bf16x8*)(brow + kb + sk + 8);
    __syncthreads();
#pragma unroll
    for (int kk = 0; kk < 64; kk += 32) {
      bf16x8 av = *(const bf16x8*)(&As[(wid * 16 + l15) * LDT + kk + q * 8]);
#pragma unroll
      for (int j = 0; j < 4; ++j) {
        bf16x8 bv = *(const bf16x8*)(&Bs[(j * 16 + l15) * LDT + kk + q * 8]);
        acc[j] = mfma16(av, bv, acc[j]);
      }
    }
    __syncthreads();
  }
#pragma unroll
  for (int j = 0; j < 4; ++j) {
    const int gn = n0 + j * 16 + l15;
#pragma unroll
    for (int r = 0; r < 4; ++r) {
      const int gm = m0 + wid * 16 + q * 4 + r;
      float v = acc[j][r];
      if (gn < 4096) Xp[(size_t)gm * 4096 + gn] = (bf16)v;
      else           Hxp[(size_t)gm * 1024 + (gn - 4096)] = v;
    }
  }
}

struct SeqArgs {
  int layer;
  const bf16 *w_hh, *hwih, *hwhh, *hyb;
  const bf16 *w_zh, *b_zh, *w_zx, *b_zx, *w_zb;
  const bf16 *w_dh, *w_dx, *w_db, *b0;
  const bf16 *Xp; const float *Hxp;
  u64 *hpub, *hhpub; float *hgpub;
  bf16 *Y0; float *outp;
  int *flags;
};

// ---------------- persistent sequential kernel: 256 steps of one layer --------------
// 128 blocks x 256 thr. blk = bq*16 + s16: bq=batch-quad (4 batches), s16=h-slice of 64.
// One grid barrier per step; all cross-block state via agent atomics (MALL), no fences.
__global__ __launch_bounds__(256) void seq_kernel(SeqArgs a) {
  __shared__ char smem[50176] __attribute__((aligned(16)));
  // hyper-role arrays (dead before BC reuse; separated by __syncthreads)
  bf16 (*hstage)[520]  = (bf16(*)[520])smem;              // 32x520 bf16 = 33280
  bf16 (*hhstage)[264] = (bf16(*)[264])(smem + 33280);    // 32x264 bf16 = 16896
  // BC-role arrays
  bf16 (*hA4)[1032]   = (bf16(*)[1032])smem;              // 8256
  bf16 (*hh2A)[264]   = (bf16(*)[264])(smem + 8256);      // 2112
  float (*RhL)[256]   = (float(*)[256])(smem + 10368);    // 4096
  float (*hgs)[1024]  = (float(*)[1024])(smem + 14464);   // 16384
  float (*zsL)[768]   = (float(*)[768])(smem + 30848);    // 12288
  float (*presL)[256] = (float(*)[256])(smem + 43136);    // 4096
  bf16 (*hbuf)[64]    = (bf16(*)[64])(smem + 47232);      // 512

  const int tid = threadIdx.x;
  const int lane = tid & 63, wid = tid >> 6;
  const int l15 = lane & 15, q = lane >> 4;
  const int blk = blockIdx.x;
  const int bq = blk >> 4, s16 = blk & 15;
  const bool isHyper = ((s16 >> 1) == bq);         // 16 blocks, spread across XCDs
  const int hj = bq * 2 + (s16 & 1);
  const int layer = a.layer;
  const bf16* whh_l  = a.w_hh + (size_t)layer * 4096 * 1024;
  const bf16* hybl   = a.hyb + (size_t)layer * 1024;
  const bf16* bzh_l  = a.b_zh + layer * 256;
  const bf16* bzx_l  = a.b_zx + layer * 256;
  const bf16* b0_l   = a.b0 + (size_t)layer * 4096;
  int* genp = a.flags;
  int* arrp = a.flags + 64;
  int* hgfp = a.flags + 2112;
  const int cb = tid >> 6, chl = tid & 63;         // cell2 ownership: batch cb, h chl

  float c_reg = 0.0f;        // main c[bq*4+cb][s16*64+chl] -- block-private
  float hc[4] = {0,0,0,0};   // hyper c[cb][chl*4+dd] -- replicated per block, deterministic

  // z B-row pointers (fixed over t)
  const bf16* zrow[12];
#pragma unroll
  for (int j = 0; j < 12; ++j) {
    int ng = wid * 12 + j, tau = ng >> 4;
    const bf16* base = (tau == 0) ? a.w_zh : (tau == 1) ? a.w_zx : a.w_zb;
    zrow[j] = base + ((size_t)layer * 256 + (ng & 15) * 16 + l15) * 256;
  }
  const bf16* rrow[4];
#pragma unroll
  for (int nt = 0; nt < 4; ++nt)
    rrow[nt] = whh_l + (size_t)(wid * 1024 + s16 * 64 + nt * 16 + l15) * 1024;
  const size_t wdo = ((size_t)(layer * 4 + wid) * 1024 + s16 * 64 + lane) * 64;
  const bf16 *pdh = a.w_dh + wdo, *pdx = a.w_dx + wdo, *pdb = a.w_db + wdo;

  for (int t = 0; t < 256; ++t) {
    if (t > 0) {
      if (tid == 0) {
        while (ildi(genp) < t) __builtin_amdgcn_s_sleep(2);
        __atomic_signal_fence(__ATOMIC_SEQ_CST);
      }
      __syncthreads();
    }

    // ---- hyper role: hg[32][n-slice 64] = h@hWih_h^T + hh@hWhh^T (M=32 MFMA) ----
    if (isHyper) {
      for (int i = tid; i < 2048; i += 256) {
        int b = i >> 6, u = i & 63;
        *(u64*)&hhstage[b][u * 4] = uld(a.hhpub + i);
      }
      for (int i = tid; i < 4096; i += 256) {
        int b = i >> 7, u = i & 127;
        *(u64*)&hstage[b][u * 4] = uld(a.hpub + ((size_t)b << 8) + u);
      }
      __syncthreads();
      const bf16* bih = a.hwih + (size_t)layer * 1024 * 2048
                        + (size_t)(hj * 64 + wid * 16 + l15) * 2048 + 1024;
      f32x4 cA = {}, cB = {};
      for (int kk = 0; kk < 512; kk += 32) {
        int ko = kk + q * 8;
        bf16x8 bv = *(const bf16x8*)(bih + ko);
        bf16x8 a0 = *(const bf16x8*)&hstage[l15][ko];
        bf16x8 a1 = *(const bf16x8*)&hstage[16 + l15][ko];
        cA = mfma16(a0, bv, cA); cB = mfma16(a1, bv, cB);
      }
      __syncthreads();
      for (int i = tid; i < 4096; i += 256) {
        int b = i >> 7, u = i & 127;
        *(u64*)&hstage[b][u * 4] = uld(a.hpub + ((size_t)b << 8) + 128 + u);
      }
      __syncthreads();
      for (int kk = 0; kk < 512; kk += 32) {
        int ko = kk + q * 8;
        bf16x8 bv = *(const bf16x8*)(bih + 512 + ko);
        bf16x8 a0 = *(const bf16x8*)&hstage[l15][ko];
        bf16x8 a1 = *(const bf16x8*)&hstage[16 + l15][ko];
        cA = mfma16(a0, bv, cA); cB = mfma16(a1, bv, cB);
      }
      const bf16* bhh = a.hwhh + (size_t)layer * 1024 * 256
                        + (size_t)(hj * 64 + wid * 16 + l15) * 256;
      for (int kk = 0; kk < 256; kk += 32) {
        int ko = kk + q * 8;
        bf16x8 bv = *(const bf16x8*)(bhh + ko);
        bf16x8 a0 = *(const bf16x8*)&hhstage[l15][ko];
        bf16x8 a1 = *(const bf16x8*)&hhstage[16 + l15][ko];
        cA = mfma16(a0, bv, cA); cB = mfma16(a1, bv, cB);
      }
      const int n = hj * 64 + wid * 16 + l15;
#pragma unroll
      for (int r = 0; r < 4; ++r) {
        fstf(a.hgpub + (q * 4 + r) * 1024 + n, cA[r]);
        fstf(a.hgpub + (16 + q * 4 + r) * 1024 + n, cB[r]);
      }
      __atomic_signal_fence(__ATOMIC_SEQ_CST);
      __builtin_amdgcn_s_waitcnt(0);
      __syncthreads();
      if (tid == 0) isti(hgfp + hj * 16, t + 1);
    }
    __syncthreads();   // hyper smem dead; safe to reuse for BC arrays

    // ---- BC: own-Rh (M=4): Rh[4b][256n] = h_own @ w_hh_slice^T ----
    for (int i = tid; i < 1024; i += 256) {
      int b = i >> 8, u = i & 255;
      *(u64*)&hA4[b][u * 4] = uld(a.hpub + ((size_t)(bq * 4 + b) << 8) + u);
    }
    __syncthreads();
    {
      f32x4 racc[4] = {};
      for (int kk = 0; kk < 1024; kk += 32) {
        const int ko = kk + q * 8;
        bf16x8 av = *(const bf16x8*)&hA4[l15 & 3][ko];
#pragma unroll
        for (int nt = 0; nt < 4; ++nt) {
          bf16x8 bv = *(const bf16x8*)(rrow[nt] + ko);
          racc[nt] = mfma16(av, bv, racc[nt]);
        }
      }
      if (lane < 16) {
#pragma unroll
        for (int nt = 0; nt < 4; ++nt)
#pragma unroll
          for (int r = 0; r < 4; ++r)
            RhL[r][wid * 64 + nt * 16 + lane] = racc[nt][r];
      }
    }
    // ---- wait for hg, stage own 4 batches ----
    if (tid < 16) { while (ildi(hgfp + tid * 16) < t + 1) __builtin_amdgcn_s_sleep(1); }
    __atomic_signal_fence(__ATOMIC_SEQ_CST);
    __syncthreads();
    for (int i = tid; i < 2048; i += 256) {
      int b = i >> 9, u = i & 511;
      *(u64*)&hgs[b][u * 2] = uld((const u64*)a.hgpub + ((size_t)(bq * 4 + b) << 9) + u);
    }
    __syncthreads();
    // ---- hyper cell (replicated per block, deterministic) + hh2 ----
    {
      const float* hgr = hgs[cb];
      const float* hxr = a.Hxp + ((size_t)(bq * 4 + cb) * 256 + t) * 1024;
      const int d0 = chl * 4;
      float hh2v[4];
#pragma unroll
      for (int dd = 0; dd < 4; ++dd) {
        int d = d0 + dd;
        float hi  = hgr[d]       + (float)hybl[d]       + hxr[d];
        float hf  = hgr[256 + d] + (float)hybl[256 + d] + hxr[256 + d];
        float hgv = hgr[512 + d] + (float)hybl[512 + d] + hxr[512 + d];
        float ho  = hgr[768 + d] + (float)hybl[768 + d] + hxr[768 + d];
        hc[dd] = sigf(hf) * hc[dd] + sigf(hi) * tanhf_fast(hgv);
        float v = sigf(ho) * tanhf_fast(hc[dd]);
        hh2v[dd] = v;
        hh2A[cb][d] = (bf16)v;
      }
      if (s16 == 0) {
        union { bf16 h[4]; u64 v; } pk;
#pragma unroll
        for (int dd = 0; dd < 4; ++dd) pk.h[dd] = (bf16)hh2v[dd];
        ust(a.hhpub + ((size_t)(bq * 4 + cb) << 6) + chl, pk.v);
      }
    }
    __syncthreads();
    // ---- z = hh2 @ wz^T (+bias), M=4 MFMA over 3x256 outputs ----
    {
      f32x4 zacc[12] = {};
      for (int kk = 0; kk < 256; kk += 32) {
        const int ko = kk + q * 8;
        bf16x8 av = *(const bf16x8*)&hh2A[l15 & 3][ko];
#pragma unroll
        for (int j = 0; j < 12; ++j) {
          bf16x8 bv = *(const bf16x8*)(zrow[j] + ko);
          zacc[j] = mfma16(av, bv, zacc[j]);
        }
      }
      if (lane < 16) {
#pragma unroll
        for (int j = 0; j < 12; ++j) {
          int ng = wid * 12 + j, tau = ng >> 4, col = (ng & 15) * 16 + lane;
          float bias = (tau == 0) ? (float)bzh_l[col] : (tau == 1) ? (float)bzx_l[col] : 0.0f;
#pragma unroll
          for (int r = 0; r < 4; ++r) zsL[r][tau * 256 + col] = zacc[j][r] + bias;
        }
      }
    }
    __syncthreads();
    // ---- d-projections + pre ----
    {
      float dH[4] = {}, dX[4] = {}, dB[4] = {};
      for (int e0 = 0; e0 < 64; e0 += 4) {
        bf16x4 wh = *(const bf16x4*)(pdh + e0);
        bf16x4 wx = *(const bf16x4*)(pdx + e0);
        bf16x4 wb = *(const bf16x4*)(pdb + e0);
        f32x4 zh_[4], zx_[4], zb_[4];
#pragma unroll
        for (int b = 0; b < 4; ++b) {
          zh_[b] = *(const f32x4*)&zsL[b][wid * 64 + e0];
          zx_[b] = *(const f32x4*)&zsL[b][256 + wid * 64 + e0];
          zb_[b] = *(const f32x4*)&zsL[b][512 + wid * 64 + e0];
        }
#pragma unroll
        for (int jj = 0; jj < 4; ++jj) {
          float whf = (float)wh[jj], wxf = (float)wx[jj], wbf = (float)wb[jj];
#pragma unroll
          for (int b = 0; b < 4; ++b) {
            dH[b] += zh_[b][jj] * whf;
            dX[b] += zx_[b][jj] * wxf;
            dB[b] += zb_[b][jj] * wbf;
          }
        }
      }
#pragma unroll
      for (int b = 0; b < 4; ++b) {
        float rh = RhL[b][wid * 64 + lane];
        float xp = (float)a.Xp[((size_t)(bq * 4 + b) * 256 + t) * 4096 + wid * 1024 + s16 * 64 + lane];
        float b0v = (float)b0_l[wid * 1024 + s16 * 64 + lane];
        presL[b][wid * 64 + lane] = dH[b] * rh + dX[b] * xp + dB[b] + b0v;
      }
    }
    __syncthreads();
    // ---- main cell + outputs ----
    {
      float iv = presL[cb][chl];
      float fv = presL[cb][64 + chl];
      float gv = presL[cb][128 + chl];
      float ov = presL[cb][192 + chl];
      c_reg = sigf(fv) * c_reg + sigf(iv) * tanhf_fast(gv);
      float hn = sigf(ov) * tanhf_fast(c_reg);
      hbuf[cb][chl] = (bf16)hn;
      const size_t oo = ((size_t)(bq * 4 + cb) * 256 + t) * 1024 + s16 * 64 + chl;
      if (layer == 0) a.Y0[oo] = (bf16)hn;
      else {
        a.outp[oo] = hn;
        if (t == 255) {
          a.outp[8388608 + (bq * 4 + cb) * 1024 + s16 * 64 + chl] = hn;
          a.outp[8421376 + (bq * 4 + cb) * 1024 + s16 * 64 + chl] = c_reg;
        }
      }
    }
    __syncthreads();
    // ---- publish own h slice, then single grid barrier ----
    if (tid < 64) {
      int b = tid >> 4, u = tid & 15;
      u64 pk = *(const u64*)&hbuf[b][u * 4];
      ust(a.hpub + ((size_t)(bq * 4 + b) << 8) + s16 * 16 + u, pk);
    }
    __atomic_signal_fence(__ATOMIC_SEQ_CST);
    __builtin_amdgcn_s_waitcnt(0);
    __syncthreads();
    if (tid == 0) isti(arrp + blk * 16, t + 1);
    if (blk == 0 && wid == 0) {   // master sweep: 64 lanes x 2 slots
      const int t1 = t + 1;
      for (;;) {
        int v0 = ildi(arrp + lane * 32);
        int v1 = ildi(arrp + lane * 32 + 16);
        if (__all((v0 >= t1) && (v1 >= t1))) break;
        __builtin_amdgcn_s_sleep(2);
      }
      __atomic_signal_fence(__ATOMIC_SEQ_CST);
      if (lane == 0) isti(genp, t1);
    }
  }
}

extern "C" void kernel_launch(void* const* d_in, const int* in_sizes, int n_in,
                              void* d_out, int out_size, void* d_ws, size_t ws_size,
                              hipStream_t stream) {
  float* outp = (float*)d_out;
  char* ws = (char*)d_ws;
  bf16*  Xp     = (bf16*) (ws);                      // 67,108,864
  float* Hxp    = (float*)(ws + 67108864ull);        // 33,554,432
  bf16*  Y0     = (bf16*) (ws + 100663296ull);       // 16,777,216
  u64*   hpub   = (u64*)  (ws + 117440512ull);       //     65,536
  u64*   hhpub  = (u64*)  (ws + 117506048ull);       //     16,384
  float* hgpub  = (float*)(ws + 117522432ull);       //    131,072
  int*   flags  = (int*)  (ws + 117653504ull);       //     16,384
  bf16* c_input = (bf16*)(ws + 117669888ull);        // 16,777,216
  bf16* c_w_ih  = (bf16*)(ws + 134447104ull);        // 16,777,216
  bf16* c_w_hh  = (bf16*)(ws + 151224320ull);        // 16,777,216
  bf16* c_hwih  = (bf16*)(ws + 168001536ull);        //  8,388,608
  bf16* c_hwhh  = (bf16*)(ws + 176390144ull);        //  1,048,576
  bf16* c_hyb   = (bf16*)(ws + 177438720ull);        //      4,096
  bf16* c_wzh   = (bf16*)(ws + 177442816ull);        //    262,144
  bf16* c_bzh   = (bf16*)(ws + 177704960ull);        //      1,024
  bf16* c_wzx   = (bf16*)(ws + 177705984ull);        //    262,144
  bf16* c_bzx   = (bf16*)(ws + 177968128ull);        //      1,024
  bf16* c_wzb   = (bf16*)(ws + 177969152ull);        //    262,144
  bf16* c_wdh   = (bf16*)(ws + 178231296ull);        //  1,048,576
  bf16* c_wdx   = (bf16*)(ws + 179279872ull);        //  1,048,576
  bf16* c_wdb   = (bf16*)(ws + 180328448ull);        //  1,048,576
  bf16* c_b0    = (bf16*)(ws + 181377024ull);        //     16,384
  int*  dflag   = (int*) (ws + 181393408ull);        //          4

  hipLaunchKernelGGL(detect_kernel, dim3(1), dim3(256), 0, stream, d_in[2], dflag);
  CvtSrc S; CvtDst D;
  for (int i = 0; i < 15; ++i) S.s[i] = d_in[i];
  D.d[0] = c_input; D.d[1] = c_w_ih; D.d[2] = c_w_hh; D.d[3] = c_hwih; D.d[4] = c_hwhh;
  D.d[5] = c_hyb;   D.d[6] = c_wzh;  D.d[7] = c_bzh;  D.d[8] = c_wzx;  D.d[9] = c_bzx;
  D.d[10] = c_wzb;  D.d[11] = c_wdh; D.d[12] = c_wdx; D.d[13] = c_wdb; D.d[14] = c_b0;
  hipLaunchKernelGGL(convert_kernel, dim3(2048), dim3(256), 0, stream, S, D, dflag);

  for (int layer = 0; layer < 2; ++layer) {
    hipLaunchKernelGGL(init_kernel, dim3(32), dim3(256), 0, stream, hpub, hhpub, flags);
    const bf16* A = (layer == 0) ? c_input : Y0;
    hipLaunchKernelGGL(gemm_pre, dim3(10240), dim3(256), 0, stream,
                       A, c_w_ih + (size_t)layer * 4096 * 1024,
                       c_hwih + (size_t)layer * 1024 * 2048, Xp, Hxp);
    SeqArgs sa;
    sa.layer = layer;
    sa.w_hh = c_w_hh; sa.hwih = c_hwih; sa.hwhh = c_hwhh; sa.hyb = c_hyb;
    sa.w_zh = c_wzh; sa.b_zh = c_bzh; sa.w_zx = c_wzx; sa.b_zx = c_bzx; sa.w_zb = c_wzb;
    sa.w_dh = c_wdh; sa.w_dx = c_wdx; sa.w_db = c_wdb; sa.b0 = c_b0;
    sa.Xp = Xp; sa.Hxp = Hxp;
    sa.hpub = hpub; sa.hhpub = hhpub; sa.hgpub = hgpub;
    sa.Y0 = Y0; sa.outp = outp;
    sa.flags = flags;
    hipLaunchKernelGGL(seq_kernel, dim3(128), dim3(256), 0, stream, sa);
  }
}